// Round 2
// baseline (202.705 us; speedup 1.0000x reference)
//
#include <hip/hip_runtime.h>
#include <math.h>

// Problem constants
#define BB   2
#define CIN  256
#define HH   48
#define WWW  48
#define OC3  768          // 3*OC channels out of the 1x1 conv
#define NG   4            // groups
#define GOC  64           // channels per group
#define C2   32           // half group channels
#define KH   7
#define KW   7
#define KK   49
#define PP   2304         // 48*48 positions
#define HALF_P 1152       // PP/2
#define HALF_S 1568       // KK*C2

// ---------------------------------------------------------------------------
// Kernel 1: 1x1 conv as GEMM.  Y2[b, p, o] = sum_c X[b, c, p] * W[o, c]
// Output position-major (B, P, 768) so attention reads are coalesced.
// Tile 128(o) x 128(p) x 16(c), 256 threads, 8x8 microtile (4 FMA/LDS-float).
// ---------------------------------------------------------------------------
__global__ __launch_bounds__(256) void conv1x1_kernel(
    const float* __restrict__ X,   // (B, 256, 2304)
    const float* __restrict__ Wm,  // (768, 256)
    float* __restrict__ Y2)        // (B, 2304, 768)
{
    __shared__ float As[16][132];  // As[kk][o]  (weight tile, transposed), +4 pad
    __shared__ float Bs[16][132];  // Bs[kk][p]

    const int tid = threadIdx.x;
    const int bn  = blockIdx.x;        // p tile (18)
    const int bm  = blockIdx.y;        // o tile (6)
    const int b   = blockIdx.z;        // batch
    const int om0 = bm * 128;
    const int pn0 = bn * 128;
    const int tx  = tid & 15;          // p microtile
    const int ty  = tid >> 4;          // o microtile

    const int arow = tid >> 1;         // 0..127 (o)
    const int acol = (tid & 1) * 8;    // 0 or 8 (c)
    const int brow = tid >> 4;         // 0..15  (c)
    const int bcol = (tid & 15) * 8;   // p

    const float* Xb = X + (size_t)b * CIN * PP;
    float acc[8][8] = {};

    for (int k0 = 0; k0 < CIN; k0 += 16) {
        float4 w0 = *(const float4*)&Wm[(size_t)(om0 + arow) * CIN + k0 + acol];
        float4 w1 = *(const float4*)&Wm[(size_t)(om0 + arow) * CIN + k0 + acol + 4];
        float4 x0 = *(const float4*)&Xb[(size_t)(k0 + brow) * PP + pn0 + bcol];
        float4 x1 = *(const float4*)&Xb[(size_t)(k0 + brow) * PP + pn0 + bcol + 4];
        __syncthreads();               // prev iter's LDS reads must finish
        As[acol + 0][arow] = w0.x;
        As[acol + 1][arow] = w0.y;
        As[acol + 2][arow] = w0.z;
        As[acol + 3][arow] = w0.w;
        As[acol + 4][arow] = w1.x;
        As[acol + 5][arow] = w1.y;
        As[acol + 6][arow] = w1.z;
        As[acol + 7][arow] = w1.w;
        *(float4*)&Bs[brow][bcol]     = x0;
        *(float4*)&Bs[brow][bcol + 4] = x1;
        __syncthreads();
        #pragma unroll
        for (int kk = 0; kk < 16; ++kk) {
            float4 a0 = *(const float4*)&As[kk][ty * 8];
            float4 a1 = *(const float4*)&As[kk][ty * 8 + 4];
            float4 b0 = *(const float4*)&Bs[kk][tx * 8];
            float4 b1 = *(const float4*)&Bs[kk][tx * 8 + 4];
            float av[8] = {a0.x, a0.y, a0.z, a0.w, a1.x, a1.y, a1.z, a1.w};
            float bv[8] = {b0.x, b0.y, b0.z, b0.w, b1.x, b1.y, b1.z, b1.w};
            #pragma unroll
            for (int i = 0; i < 8; ++i)
                #pragma unroll
                for (int j = 0; j < 8; ++j)
                    acc[i][j] += av[i] * bv[j];
        }
    }

    float* Yb = Y2 + (size_t)b * PP * OC3;
    #pragma unroll
    for (int j = 0; j < 8; ++j) {
        int p = pn0 + tx * 8 + j;
        *(float4*)&Yb[(size_t)p * OC3 + om0 + ty * 8] =
            make_float4(acc[0][j], acc[1][j], acc[2][j], acc[3][j]);
        *(float4*)&Yb[(size_t)p * OC3 + om0 + ty * 8 + 4] =
            make_float4(acc[4][j], acc[5][j], acc[6][j], acc[7][j]);
    }
}

// ---------------------------------------------------------------------------
// Kernel 2: attention. One wave per (b, g, p'); block = 4 consecutive p'.
// Key scramble (from concat(axis=1)+row-major reshape):
//   t = p' >= 1152; q' = p' - t*1152; g2 = 2g + t
//   s = k'*64 + lane; h1 = s >= 1568; r = s - h1*1568
//   source pos p = 2q' + h1 (same spatial row since p even, W even)
//   k = r>>5 (tap), c = r&31
//   g2 < 4 : chan = 256 + g2*64 + c,        + rpe_h[g2, i, c]
//   g2 >= 4: chan = 256 + (g2-4)*64 + 32+c, + rpe_w[g2-4, j, c]
//   OOB patch reads contribute 0 + rpe.
// Logit reduction: transpose-reduce tree (63 pair-ops total vs 49 butterflies).
// Stage 1 fused into the chunk loop to cap live registers at ~33.
// ---------------------------------------------------------------------------
__global__ __launch_bounds__(256) void attn_kernel(
    const float* __restrict__ Y2,     // (B, 2304, 768)
    const float* __restrict__ rpe_h,  // (4,1,7,1,32)
    const float* __restrict__ rpe_w,  // (4,1,1,7,32)
    float* __restrict__ out)          // (B, 256, 48, 48)
{
    __shared__ float xpose[4][65];

    const int tid  = threadIdx.x;
    const int lane = tid & 63;
    const int w    = tid >> 6;
    const int wid  = blockIdx.x * 4 + w;            // 0 .. 18431
    const int pq   = wid % PP;                      // p'
    const int g    = (wid / PP) & (NG - 1);
    const int b    = wid / (PP * NG);
    const int ph   = pq / WWW;
    const int pw   = pq % WWW;

    const float* Yb = Y2 + (size_t)b * PP * OC3;

    // query: center tap, coalesced 64 channels
    const float q = Yb[(size_t)pq * OC3 + g * GOC + lane];

    // scramble params (wave-uniform)
    const int t   = (pq >= HALF_P) ? 1 : 0;
    const int qpr = pq - t * HALF_P;
    const int p0  = 2 * qpr;
    const int ph0 = p0 / WWW;
    const int pw0 = p0 % WWW;            // p0 even => p0+1 same row
    const int g2  = 2 * g + t;
    const bool use_h = (g2 < NG);
    const int  kch   = use_h ? (CIN + g2 * GOC) : (CIN + (g2 - NG) * GOC + C2);
    const float* rpe = use_h ? (rpe_h + g2 * KH * C2) : (rpe_w + (g2 - NG) * KW * C2);

    auto chunkprod = [&](int kp) -> float {
        int s  = kp * 64 + lane;
        int h1 = (s >= HALF_S) ? 1 : 0;
        int r  = s - h1 * HALF_S;
        int k  = r >> 5;
        int c  = r & 31;
        int i  = (k * 37) >> 8;          // k/7 for k<49
        int j2 = k - i * 7;
        int yh = ph0 + i - 3;
        int yw = pw0 + h1 + j2 - 3;
        float kv = 0.f;
        if ((unsigned)yh < 48u && (unsigned)yw < 48u)
            kv = Yb[(size_t)(yh * WWW + yw) * OC3 + kch + c];
        int ij = use_h ? i : j2;
        kv += rpe[ij * C2 + c];
        return q * kv;
    };

    // ---- logits: chunk loop with fused stage-1 pair-combine ----
    float sv[32];
    #pragma unroll
    for (int j = 0; j < 32; ++j) {
        if (2 * j >= KK) { sv[j] = 0.f; continue; }
        float p0v = chunkprod(2 * j);
        float p1v = (2 * j + 1 < KK) ? chunkprod(2 * j + 1) : 0.f;
        float u  = (lane & 1) ? p1v : p0v;
        float ww = (lane & 1) ? p0v : p1v;
        sv[j] = u + __shfl_xor(ww, 1, 64);
    }
    // ---- remaining tree stages: after all stages, lane l holds logit[l] ----
    #pragma unroll
    for (int d = 2; d < 64; d <<= 1) {
        #pragma unroll
        for (int i = 0; i < 32; i += d) {
            float a  = sv[i], bb = sv[i + d / 2];
            float u  = (lane & d) ? bb : a;
            float ww = (lane & d) ? a : bb;
            sv[i] = u + __shfl_xor(ww, d, 64);
        }
    }
    const float logit = sv[0];   // lane l: logit of chunk l (l<49), else 0

    // ---- softmax over lanes 0..48 (zero-pad lanes are harmless in max) ----
    float mx = logit;
    #pragma unroll
    for (int d = 1; d < 64; d <<= 1)
        mx = fmaxf(mx, __shfl_xor(mx, d, 64));
    float e = (lane < KK) ? __expf(logit - mx) : 0.f;
    float ssum = e;
    #pragma unroll
    for (int d = 1; d < 64; d <<= 1)
        ssum += __shfl_xor(ssum, d, 64);
    const float att = e / ssum;

    // ---- value accumulation: lane = output channel ----
    float acc = 0.f;
    const int vch = 2 * CIN + g * GOC + lane;
    #pragma unroll
    for (int k = 0; k < KK; ++k) {
        float ak = __shfl(att, k, 64);
        int i = k / 7, j = k % 7;        // compile-time (unrolled)
        int yh = ph + i - 3;
        int yw = pw + j - 3;
        if ((unsigned)yh < 48u && (unsigned)yw < 48u)
            acc += ak * Yb[(size_t)(yh * WWW + yw) * OC3 + vch];
    }

    // ---- LDS transpose + grouped store (16B segments instead of 4B scatter)
    xpose[w][lane] = acc;
    __syncthreads();
    const int wid0 = blockIdx.x * 4;
    const int pq0  = wid0 % PP;
    const int g0   = (wid0 / PP) & (NG - 1);
    const int b0   = wid0 / (PP * NG);
    const int ch   = tid >> 2;           // 0..63
    const int w2   = tid & 3;
    out[((size_t)b0 * 256 + g0 * GOC + ch) * PP + pq0 + w2] = xpose[w2][ch];
}

// ---------------------------------------------------------------------------
extern "C" void kernel_launch(void* const* d_in, const int* in_sizes, int n_in,
                              void* d_out, int out_size, void* d_ws, size_t ws_size,
                              hipStream_t stream)
{
    const float* x  = (const float*)d_in[0];   // (2,256,48,48)
    const float* w  = (const float*)d_in[1];   // (768,256)
    const float* rh = (const float*)d_in[2];   // (4,1,7,1,32)
    const float* rw = (const float*)d_in[3];   // (4,1,1,7,32)
    float* Y2 = (float*)d_ws;                  // B*2304*768*4 = 14.2 MB

    dim3 gridC(PP / 128, OC3 / 128, BB);       // 18 x 6 x 2
    conv1x1_kernel<<<gridC, 256, 0, stream>>>(x, w, Y2);

    const int nwaves = BB * NG * PP;           // 18432
    attn_kernel<<<nwaves / 4, 256, 0, stream>>>(Y2, rh, rw, (float*)d_out);
}

// Round 3
// 157.930 us; speedup vs baseline: 1.2835x; 1.2835x over previous
//
#include <hip/hip_runtime.h>
#include <math.h>

// Problem constants
#define BB   2
#define CIN  256
#define OC3  768          // 3*OC channels out of the 1x1 conv
#define NG   4            // groups
#define GOC  64
#define C2   32
#define KK   49
#define PP   2304         // 48*48 positions
#define HALF_P 1152

// Guarded Y2 layout: rows -3..50 (54), cols -3..51 at stride 56, 768 ch.
// OOB window taps land in zeroed guard cells => pad-then-rpe semantics free.
#define RS      56
#define BROWS   54
#define BSTRIDE (BROWS * RS * OC3)          // floats per batch = 2,322,432
#define IOFF    ((3 * RS + 3) * OC3)        // interior (0,0) offset

// ---------------------------------------------------------------------------
// Kernel 1: 1x1 conv GEMM. Y2[b, (h,w), o] = sum_c X[b,c,p] * W[o,c]
// Tile 128(o) x 64(p) x 16(c), 256 threads, 8x4 microtile (32 acc VGPRs).
// Grid 6 x 36 x 2 = 432 blocks. LDS layouts conflict-free (see notes).
// ---------------------------------------------------------------------------
__global__ __launch_bounds__(256) void conv1x1_kernel(
    const float* __restrict__ X,   // (B, 256, 2304)
    const float* __restrict__ Wm,  // (768, 256)
    float* __restrict__ Y2)        // guarded layout
{
    __shared__ float As[16][132];  // [c][o], o=128 (+4 pad); reads broadcast
    __shared__ float Bs[16][68];   // [c][p], p=64 (+4 pad); reads stride-4 → all banks

    const int tid = threadIdx.x;
    const int bm  = blockIdx.x;        // o tile (6)
    const int bn  = blockIdx.y;        // p tile (36)
    const int b   = blockIdx.z;
    const int om0 = bm * 128;
    const int pn0 = bn * 64;
    const int tx  = tid & 15;          // p microtile (4 each)
    const int ty  = tid >> 4;          // o microtile (8 each)

    const int arow = tid >> 1;         // 0..127 (o)
    const int acol = (tid & 1) * 8;    // 0 or 8 (c)
    const int brow = tid >> 4;         // 0..15  (c)
    const int bcol = (tid & 15) * 4;   // p

    const float* Xb = X + (size_t)b * CIN * PP;
    float acc[8][4] = {};

    for (int k0 = 0; k0 < CIN; k0 += 16) {
        float4 w0 = *(const float4*)&Wm[(size_t)(om0 + arow) * CIN + k0 + acol];
        float4 w1 = *(const float4*)&Wm[(size_t)(om0 + arow) * CIN + k0 + acol + 4];
        float4 x0 = *(const float4*)&Xb[(size_t)(k0 + brow) * PP + pn0 + bcol];
        __syncthreads();               // prev iter's LDS reads must finish
        As[acol + 0][arow] = w0.x;
        As[acol + 1][arow] = w0.y;
        As[acol + 2][arow] = w0.z;
        As[acol + 3][arow] = w0.w;
        As[acol + 4][arow] = w1.x;
        As[acol + 5][arow] = w1.y;
        As[acol + 6][arow] = w1.z;
        As[acol + 7][arow] = w1.w;
        *(float4*)&Bs[brow][bcol] = x0;
        __syncthreads();
        #pragma unroll
        for (int kk = 0; kk < 16; ++kk) {
            float4 a0 = *(const float4*)&As[kk][ty * 8];
            float4 a1 = *(const float4*)&As[kk][ty * 8 + 4];
            float4 b0 = *(const float4*)&Bs[kk][tx * 4];
            float av[8] = {a0.x, a0.y, a0.z, a0.w, a1.x, a1.y, a1.z, a1.w};
            float bv[4] = {b0.x, b0.y, b0.z, b0.w};
            #pragma unroll
            for (int i = 0; i < 8; ++i)
                #pragma unroll
                for (int j = 0; j < 4; ++j)
                    acc[i][j] = fmaf(av[i], bv[j], acc[i][j]);
        }
    }

    float* Yb = Y2 + (size_t)b * BSTRIDE + IOFF;
    #pragma unroll
    for (int j = 0; j < 4; ++j) {
        int p = pn0 + tx * 4 + j;
        int h = p / 48, w = p - h * 48;
        size_t base = (size_t)(h * RS + w) * OC3 + om0 + ty * 8;
        *(float4*)&Yb[base] =
            make_float4(acc[0][j], acc[1][j], acc[2][j], acc[3][j]);
        *(float4*)&Yb[base + 4] =
            make_float4(acc[4][j], acc[5][j], acc[6][j], acc[7][j]);
    }
}

// ---------------------------------------------------------------------------
// Kernel 2: attention. One wave per (b,g,p'). XCD-swizzled block id.
// Per-chunk algebra (verified round 1/2): c = lane&31 always; per half
// hv=lane>>5: m = 2l+hv, h1 = m>=49, k = m-49*h1, i=k/7, j=k%7 — ALL
// compile-time per (l,hv). Zero-guarded Y2 removes bounds checks; OOB
// reads give 0 then +rpe, matching reference pad-then-rpe.
// ---------------------------------------------------------------------------
__global__ __launch_bounds__(256) void attn_kernel(
    const float* __restrict__ Y2,
    const float* __restrict__ rpe_h,  // (4,1,7,1,32)
    const float* __restrict__ rpe_w,  // (4,1,1,7,32)
    float* __restrict__ out)          // (B, 256, 48, 48)
{
    __shared__ float xpose[4][65];

    const int tid  = threadIdx.x;
    const int lane = tid & 63;
    const int w    = tid >> 6;
    // XCD swizzle: blocks with same (bx&7) get a contiguous wid range so each
    // XCD's L2 sees ~1.8 MB (one (b,g) slice) instead of the full 18.6 MB.
    const int bx     = blockIdx.x;
    const int wblock = (bx & 7) * 576 + (bx >> 3);
    const int wid    = wblock * 4 + w;              // 0 .. 18431
    const int pq   = wid % PP;
    const int g    = (wid / PP) & (NG - 1);
    const int b    = wid / (PP * NG);
    const int ph   = pq / 48;
    const int pw   = pq - ph * 48;

    const float* Yb = Y2 + (size_t)b * BSTRIDE + IOFF;

    // query: center tap, coalesced 64 channels
    const float q = Yb[(size_t)(ph * RS + pw) * OC3 + g * GOC + lane];

    // scramble params (wave-uniform)
    const int t   = (pq >= HALF_P) ? 1 : 0;
    const int qpr = pq - t * HALF_P;
    const int p0  = 2 * qpr;
    const int ph0 = p0 / 48;
    const int pw0 = p0 - ph0 * 48;       // p0 even => p0+1 same row
    const int g2  = 2 * g + t;
    const bool use_h = (g2 < NG);
    const int  kch   = use_h ? (CIN + g2 * GOC) : (CIN + (g2 - NG) * GOC + C2);
    const float* rb  = use_h ? (rpe_h + g2 * 7 * C2) : (rpe_w + (g2 - NG) * 7 * C2);

    const int  c  = lane & 31;
    const bool hi = (lane >= 32);

    // preload the 7 rpe rows this wave can touch (L1-hot, once)
    float rv[7];
    #pragma unroll
    for (int ij = 0; ij < 7; ++ij) rv[ij] = rb[ij * C2 + c];

    // per-lane key base (element offset folded into pointer)
    const float* kb = Yb + (size_t)(ph0 * RS + pw0) * OC3 + kch + c;

    auto chunkprod = [&](int l) -> float {
        // all of the below folds to constants (l is a literal after unroll)
        int m0 = 2 * l,     h10 = (m0 >= KK), k0 = m0 - KK * h10;
        int m1 = 2 * l + 1, h11 = (m1 >= KK), k1 = m1 - KK * h11;
        int i0 = k0 / 7, j0 = k0 % 7, i1 = k1 / 7, j1 = k1 % 7;
        int d0 = ((i0 - 3) * RS + (h10 + j0 - 3)) * OC3;
        int d1 = ((i1 - 3) * RS + (h11 + j1 - 3)) * OC3;
        float kv = kb[hi ? d1 : d0];
        float r0 = use_h ? rv[i0] : rv[j0];
        float r1 = use_h ? rv[i1] : rv[j1];
        kv += hi ? r1 : r0;
        return q * kv;
    };

    // ---- logits: chunk loop with fused stage-1 pair-combine ----
    float sv[32];
    #pragma unroll
    for (int jj = 0; jj < 32; ++jj) {
        if (2 * jj >= KK) { sv[jj] = 0.f; continue; }
        float pa = chunkprod(2 * jj);
        float pb = (2 * jj + 1 < KK) ? chunkprod(2 * jj + 1) : 0.f;
        float u  = (lane & 1) ? pb : pa;
        float ww = (lane & 1) ? pa : pb;
        sv[jj] = u + __shfl_xor(ww, 1, 64);
    }
    #pragma unroll
    for (int d = 2; d < 64; d <<= 1) {
        #pragma unroll
        for (int i = 0; i < 32; i += d) {
            float a  = sv[i], bb = sv[i + d / 2];
            float u  = (lane & d) ? bb : a;
            float ww = (lane & d) ? a : bb;
            sv[i] = u + __shfl_xor(ww, d, 64);
        }
    }
    const float logit = sv[0];   // lane l: logit of tap l (l<49), else 0

    // ---- softmax over lanes (pad lanes hold 0; harmless, matches R1/R2) ----
    float mx = logit;
    #pragma unroll
    for (int d = 1; d < 64; d <<= 1)
        mx = fmaxf(mx, __shfl_xor(mx, d, 64));
    float e = (lane < KK) ? __expf(logit - mx) : 0.f;
    float ssum = e;
    #pragma unroll
    for (int d = 1; d < 64; d <<= 1)
        ssum += __shfl_xor(ssum, d, 64);
    const float att = e / ssum;

    // ---- value accumulation: lane = output channel; readlane (VALU) not shfl
    float acc = 0.f;
    const float* vb = Yb + (size_t)(ph * RS + pw) * OC3 + 2 * CIN + g * GOC + lane;
    #pragma unroll
    for (int k = 0; k < KK; ++k) {
        int i = k / 7, j = k % 7;                  // compile-time
        int doff = ((i - 3) * RS + (j - 3)) * OC3; // compile-time
        float ak = __uint_as_float(
            __builtin_amdgcn_readlane(__float_as_uint(att), k));
        acc = fmaf(ak, vb[doff], acc);
    }

    // ---- LDS transpose + grouped 16B stores ----
    xpose[w][lane] = acc;
    __syncthreads();
    const int wid0 = wblock * 4;           // 4 wids of this block share b,g
    const int pq0  = wid0 % PP;
    const int g0   = (wid0 / PP) & (NG - 1);
    const int b0   = wid0 / (PP * NG);
    const int ch   = tid >> 2;
    const int w2   = tid & 3;
    out[((size_t)b0 * 256 + g0 * GOC + ch) * PP + pq0 + w2] = xpose[w2][ch];
}

// ---------------------------------------------------------------------------
extern "C" void kernel_launch(void* const* d_in, const int* in_sizes, int n_in,
                              void* d_out, int out_size, void* d_ws, size_t ws_size,
                              hipStream_t stream)
{
    const float* x  = (const float*)d_in[0];   // (2,256,48,48)
    const float* w  = (const float*)d_in[1];   // (768,256)
    const float* rh = (const float*)d_in[2];   // (4,1,7,1,32)
    const float* rw = (const float*)d_in[3];   // (4,1,1,7,32)
    float* Y2 = (float*)d_ws;                  // 2 * 2,322,432 floats = 18.58 MB

    size_t need = (size_t)BB * BSTRIDE * sizeof(float);
    hipMemsetAsync(d_ws, 0, need <= ws_size ? need : ws_size, stream);

    dim3 gridC(OC3 / 128, PP / 64, BB);        // 6 x 36 x 2 = 432 blocks
    conv1x1_kernel<<<gridC, 256, 0, stream>>>(x, w, Y2);

    const int nwaves = BB * NG * PP;           // 18432
    attn_kernel<<<nwaves / 4, 256, 0, stream>>>(Y2, rh, rw, (float*)d_out);
}

// Round 5
// 123.588 us; speedup vs baseline: 1.6402x; 1.2779x over previous
//
#include <hip/hip_runtime.h>

// Problem constants
#define BB   2
#define CIN  256
#define OC3  768
#define NG   4
#define GOC  64
#define C2   32
#define KK   49
#define PP   2304
#define HALF_P 1152

// Guarded Y2 layout: rows -3..50 (54), cols -3..52 at stride 56, 768 ch.
#define RS      56
#define BROWS   54
#define BSTRIDE (BROWS * RS * OC3)          // floats per batch = 2,322,432
#define IOFF    ((3 * RS + 3) * OC3)

// Workspace layout (bytes):
//   [0, 18579456)            Y2   fp32 guarded (memset 0)
//   [18579456, 23298048)     Xt   bf16 (B,2304,512)  hi|lo along k
//   [23298048, 24084480)     Wt   bf16 (768,512)     hi|lo along k
#define Y2_BYTES  (BB * BROWS * RS * OC3 * 4)
#define XT_OFF    Y2_BYTES
#define WT_OFF    (XT_OFF + BB * PP * 512 * 2)

typedef __attribute__((ext_vector_type(8))) short bf16x8;
typedef __attribute__((ext_vector_type(4))) float f32x4;

static __device__ __forceinline__ unsigned short f2bf_rne(float x) {
    unsigned int u = __float_as_uint(x);
    unsigned int r = u + 0x7FFFu + ((u >> 16) & 1u);
    return (unsigned short)(r >> 16);
}
static __device__ __forceinline__ float bf2f(unsigned short h) {
    return __uint_as_float(((unsigned int)h) << 16);
}

// ---------------------------------------------------------------------------
// Converter: W (768,256) fp32 -> Wt (768,512) bf16 split hi|lo.
// ---------------------------------------------------------------------------
__global__ __launch_bounds__(256) void convert_w(
    const float* __restrict__ W, short* __restrict__ Wt)
{
    int t = blockIdx.x * 256 + threadIdx.x;       // 0 .. 196607
    int o = t >> 8, c = t & 255;
    float v = W[t];
    unsigned short hi = f2bf_rne(v);
    unsigned short lo = f2bf_rne(v - bf2f(hi));
    Wt[(size_t)o * 512 + c]       = (short)hi;
    Wt[(size_t)o * 512 + 256 + c] = (short)lo;
}

// ---------------------------------------------------------------------------
// Converter: X (B,256,2304) fp32 -> Xt (B,2304,512) bf16 split hi|lo.
// LDS-transposed for coalescing on both sides.
// ---------------------------------------------------------------------------
__global__ __launch_bounds__(256) void convert_x(
    const float* __restrict__ X, short* __restrict__ Xt)
{
    __shared__ float tile[64][65];
    const int t  = threadIdx.x;
    const int p0 = blockIdx.x * 64;   // 36
    const int c0 = blockIdx.y * 64;   // 4
    const int b  = blockIdx.z;

    const float* Xb = X + (size_t)b * CIN * PP;
    #pragma unroll
    for (int r = 0; r < 16; ++r) {
        int idx = r * 256 + t;
        int c = idx >> 6, p = idx & 63;
        tile[c][p] = Xb[(size_t)(c0 + c) * PP + p0 + p];
    }
    __syncthreads();
    short* Xo = Xt + (size_t)b * PP * 512;
    #pragma unroll
    for (int r = 0; r < 16; ++r) {
        int idx = r * 256 + t;
        int p = idx >> 6, c = idx & 63;
        float v = tile[c][p];
        unsigned short hi = f2bf_rne(v);
        unsigned short lo = f2bf_rne(v - bf2f(hi));
        size_t base = (size_t)(p0 + p) * 512 + c0 + c;
        Xo[base]       = (short)hi;
        Xo[base + 256] = (short)lo;
    }
}

// ---------------------------------------------------------------------------
// Kernel 1: conv as split-bf16 MFMA GEMM with THREE-TERM product:
//   C = W_hi*X_hi + W_hi*X_lo + W_lo*X_hi   (lo*lo term ~2^-18, dropped)
// Virtual K=768 over the K=512 [hi|lo] buffers via wave-uniform remap:
//   k0 in [0,256):   wk=k0      (W hi), xk=k0      (X hi)
//   k0 in [256,512): wk=k0-256  (W hi), xk=k0      (X lo)
//   k0 in [512,768): wk=k0-256  (W lo), xk=k0-512  (X hi)
// Tile 128(o) x 128(p), 4 waves, each a 64x64 quadrant of 16x16x32 MFMAs.
// ---------------------------------------------------------------------------
#define LDA 40   // shorts per LDS row (32 + 8 pad)

__global__ __launch_bounds__(256, 2) void conv_mfma(
    const short* __restrict__ Wt,   // (768, 512)
    const short* __restrict__ Xt,   // (B, 2304, 512)
    float* __restrict__ Y2)
{
    __shared__ short As[128 * LDA];   // [o][k]
    __shared__ short Bs[128 * LDA];   // [p][k]

    const int tid = threadIdx.x;
    const int bn  = blockIdx.x;       // p tile (18)
    const int bm  = blockIdx.y;       // o tile (6)
    const int b   = blockIdx.z;
    const int om0 = bm * 128, pn0 = bn * 128;

    const int lane = tid & 63, w = tid >> 6;
    const int oq = (w >> 1) * 64, pq = (w & 1) * 64;
    const int ln15 = lane & 15, q = lane >> 4;

    const int srow = tid >> 1;
    const int soff = (tid & 1) * 16;  // shorts
    const short* Wg = Wt + (size_t)(om0 + srow) * 512 + soff;
    const short* Xg = Xt + (size_t)b * PP * 512 + (size_t)(pn0 + srow) * 512 + soff;
    short* Asw = &As[srow * LDA + soff];
    short* Bsw = &Bs[srow * LDA + soff];

    f32x4 acc[4][4] = {};

    for (int k0 = 0; k0 < 768; k0 += 32) {
        const int wk = (k0 < 256) ? k0 : k0 - 256;   // W: hi, hi, lo
        const int xk = (k0 < 512) ? k0 : k0 - 512;   // X: hi, lo, hi
        uint4 wa = *(const uint4*)(Wg + wk);
        uint4 wb = *(const uint4*)(Wg + wk + 8);
        uint4 xa = *(const uint4*)(Xg + xk);
        uint4 xb = *(const uint4*)(Xg + xk + 8);
        __syncthreads();
        *(uint4*)(Asw)     = wa;
        *(uint4*)(Asw + 8) = wb;
        *(uint4*)(Bsw)     = xa;
        *(uint4*)(Bsw + 8) = xb;
        __syncthreads();

        bf16x8 af[4], bf[4];
        #pragma unroll
        for (int i = 0; i < 4; ++i) {
            af[i] = *(const bf16x8*)&As[(oq + i * 16 + ln15) * LDA + q * 8];
            bf[i] = *(const bf16x8*)&Bs[(pq + i * 16 + ln15) * LDA + q * 8];
        }
        #pragma unroll
        for (int i = 0; i < 4; ++i)
            #pragma unroll
            for (int j = 0; j < 4; ++j)
                acc[i][j] = __builtin_amdgcn_mfma_f32_16x16x32_bf16(
                    af[i], bf[j], acc[i][j], 0, 0, 0);
    }

    // Epilogue: D[m=o][n=p]; lane holds col p=ln15, rows o=q*4..q*4+3 (contig)
    float* Yb = Y2 + (size_t)b * BSTRIDE + IOFF;
    #pragma unroll
    for (int i = 0; i < 4; ++i) {
        #pragma unroll
        for (int j = 0; j < 4; ++j) {
            int o = om0 + oq + i * 16 + q * 4;
            int p = pn0 + pq + j * 16 + ln15;
            int h = p / 48, ww = p - h * 48;
            *(f32x4*)&Yb[(size_t)(h * RS + ww) * OC3 + o] = acc[i][j];
        }
    }
}

// ---------------------------------------------------------------------------
// Kernel 2: attention. One wave per (b,g,p'). XCD-swizzled.
// Scramble algebra verified rounds 1-3. All per-chunk offsets compile-time;
// rpe via named scalars (no indexed private arrays -> no LDS demotion).
// ---------------------------------------------------------------------------
struct TagH { static constexpr bool value = true;  };
struct TagW { static constexpr bool value = false; };

__global__ __launch_bounds__(256, 4) void attn_kernel(
    const float* __restrict__ Y2,
    const float* __restrict__ rpe_h,  // (4,1,7,1,32)
    const float* __restrict__ rpe_w,  // (4,1,1,7,32)
    float* __restrict__ out)          // (B, 256, 48, 48)
{
    __shared__ float xpose[4][65];

    const int tid  = threadIdx.x;
    const int lane = tid & 63;
    const int w    = tid >> 6;
    const int bx     = blockIdx.x;
    const int wblock = (bx & 7) * 576 + (bx >> 3);
    const int wid    = wblock * 4 + w;
    const int pq   = wid % PP;
    const int g    = (wid / PP) & (NG - 1);
    const int b    = wid / (PP * NG);
    const int ph   = pq / 48;
    const int pw   = pq - ph * 48;

    const float* Yb = Y2 + (size_t)b * BSTRIDE + IOFF;

    const float qv = Yb[(size_t)(ph * RS + pw) * OC3 + g * GOC + lane];

    const int t   = (pq >= HALF_P) ? 1 : 0;
    const int qpr = pq - t * HALF_P;
    const int p0  = 2 * qpr;
    const int ph0 = p0 / 48;
    const int pw0 = p0 - ph0 * 48;
    const int g2  = 2 * g + t;
    const bool use_h = (g2 < NG);
    const int  kch   = use_h ? (CIN + g2 * GOC) : (CIN + (g2 - NG) * GOC + C2);
    const float* rb  = use_h ? (rpe_h + g2 * 7 * C2) : (rpe_w + (g2 - NG) * 7 * C2);

    const int  c  = lane & 31;
    const bool hi = (lane >= 32);

    const float R0 = rb[0 * C2 + c], R1 = rb[1 * C2 + c], R2 = rb[2 * C2 + c],
                R3 = rb[3 * C2 + c], R4 = rb[4 * C2 + c], R5 = rb[5 * C2 + c],
                R6 = rb[6 * C2 + c];

    const float* kb = Yb + (size_t)(ph0 * RS + pw0) * OC3 + kch + c;

    auto rget = [&](int idx) -> float {
        return idx == 0 ? R0 : idx == 1 ? R1 : idx == 2 ? R2 :
               idx == 3 ? R3 : idx == 4 ? R4 : idx == 5 ? R5 : R6;
    };

    auto tree = [&](auto tag) -> float {
        constexpr bool UH = decltype(tag)::value;
        auto chunkprod = [&](int l) -> float {
            int m0 = 2 * l,     h10 = (m0 >= KK), k0 = m0 - KK * h10;
            int m1 = 2 * l + 1, h11 = (m1 >= KK), k1 = m1 - KK * h11;
            int i0 = k0 / 7, j0 = k0 % 7, i1 = k1 / 7, j1 = k1 % 7;
            int d0 = ((i0 - 3) * RS + (h10 + j0 - 3)) * OC3;
            int d1 = ((i1 - 3) * RS + (h11 + j1 - 3)) * OC3;
            float kv = kb[hi ? d1 : d0];
            float ra = UH ? rget(i0) : rget(j0);
            float rc = UH ? rget(i1) : rget(j1);
            kv += hi ? rc : ra;
            return qv * kv;
        };
        float sv[32];
        #pragma unroll
        for (int jj = 0; jj < 32; ++jj) {
            if (2 * jj >= KK) { sv[jj] = 0.f; continue; }
            float pa = chunkprod(2 * jj);
            float pb = (2 * jj + 1 < KK) ? chunkprod(2 * jj + 1) : 0.f;
            float u  = (lane & 1) ? pb : pa;
            float ww = (lane & 1) ? pa : pb;
            sv[jj] = u + __shfl_xor(ww, 1, 64);
        }
        #pragma unroll
        for (int d = 2; d < 64; d <<= 1) {
            #pragma unroll
            for (int i = 0; i < 32; i += d) {
                float a  = sv[i], bb = sv[i + d / 2];
                float u  = (lane & d) ? bb : a;
                float ww = (lane & d) ? a : bb;
                sv[i] = u + __shfl_xor(ww, d, 64);
            }
        }
        return sv[0];
    };

    const float logit = use_h ? tree(TagH{}) : tree(TagW{});

    float mx = logit;
    #pragma unroll
    for (int d = 1; d < 64; d <<= 1)
        mx = fmaxf(mx, __shfl_xor(mx, d, 64));
    float e = (lane < KK) ? __expf(logit - mx) : 0.f;
    float ssum = e;
    #pragma unroll
    for (int d = 1; d < 64; d <<= 1)
        ssum += __shfl_xor(ssum, d, 64);
    const float att = e / ssum;

    float acc = 0.f;
    const float* vb = Yb + (size_t)(ph * RS + pw) * OC3 + 2 * CIN + g * GOC + lane;
    #pragma unroll
    for (int k = 0; k < KK; ++k) {
        int i = k / 7, j = k % 7;
        int doff = ((i - 3) * RS + (j - 3)) * OC3;
        float ak = __uint_as_float(
            __builtin_amdgcn_readlane(__float_as_uint(att), k));
        acc = fmaf(ak, vb[doff], acc);
    }

    xpose[w][lane] = acc;
    __syncthreads();
    const int wid0 = wblock * 4;
    const int pq0  = wid0 % PP;
    const int g0   = (wid0 / PP) & (NG - 1);
    const int b0   = wid0 / (PP * NG);
    const int ch   = tid >> 2;
    const int w2   = tid & 3;
    out[((size_t)b0 * 256 + g0 * GOC + ch) * PP + pq0 + w2] = xpose[w2][ch];
}

// ---------------------------------------------------------------------------
extern "C" void kernel_launch(void* const* d_in, const int* in_sizes, int n_in,
                              void* d_out, int out_size, void* d_ws, size_t ws_size,
                              hipStream_t stream)
{
    const float* x  = (const float*)d_in[0];
    const float* w  = (const float*)d_in[1];
    const float* rh = (const float*)d_in[2];
    const float* rw = (const float*)d_in[3];

    float* Y2 = (float*)d_ws;
    short* Xt = (short*)((char*)d_ws + XT_OFF);
    short* Wt = (short*)((char*)d_ws + WT_OFF);

    hipMemsetAsync(d_ws, 0, Y2_BYTES, stream);   // zero guard cells

    convert_w<<<768, 256, 0, stream>>>(w, Wt);
    convert_x<<<dim3(36, 4, BB), 256, 0, stream>>>(x, Xt);

    conv_mfma<<<dim3(18, 6, BB), 256, 0, stream>>>(Wt, Xt, Y2);

    attn_kernel<<<(BB * NG * PP) / 4, 256, 0, stream>>>(Y2, rh, rw, (float*)d_out);
}

// Round 7
// 117.403 us; speedup vs baseline: 1.7266x; 1.0527x over previous
//
#include <hip/hip_runtime.h>

// Problem constants
#define BB   2
#define CIN  256
#define OC3  768
#define NG   4
#define GOC  64
#define C2   32
#define KK   49
#define PP   2304
#define HALF_P 1152

// Guarded Y2 layout: rows -3..50 (54), cols -3..52 at stride 56, 768 ch.
#define RS      56
#define BROWS   54
#define BSTRIDE (BROWS * RS * OC3)          // floats per batch = 2,322,432
#define IOFF    ((3 * RS + 3) * OC3)

// Workspace layout (bytes)
#define Y2_BYTES  (BB * BROWS * RS * OC3 * 4)
#define XT_OFF    Y2_BYTES
#define WT_OFF    (XT_OFF + BB * PP * 512 * 2)

typedef __attribute__((ext_vector_type(8))) short bf16x8;
typedef __attribute__((ext_vector_type(4))) float f32x4;

static __device__ __forceinline__ unsigned short f2bf_rne(float x) {
    unsigned int u = __float_as_uint(x);
    unsigned int r = u + 0x7FFFu + ((u >> 16) & 1u);
    return (unsigned short)(r >> 16);
}
static __device__ __forceinline__ float bf2f(unsigned short h) {
    return __uint_as_float(((unsigned int)h) << 16);
}

// ---------------------------------------------------------------------------
// Zero only the guard cells of Y2 (2.2 MB/batch instead of 9.3 MB/batch).
// ---------------------------------------------------------------------------
#define ROW4  (RS * OC3 / 4)       // 10752 float4 per spatial row
#define REG1  (6 * ROW4)           // 6 full guard rows (0,1,2,51,52,53)
#define COLS4 (OC3 / 4)            // 192 float4 per cell
__global__ __launch_bounds__(256) void zero_guard(float* __restrict__ Y2)
{
    const int idx = blockIdx.x * 256 + threadIdx.x;   // 0 .. 138239
    const int b   = blockIdx.y;
    float4* Yb = (float4*)(Y2 + (size_t)b * BSTRIDE);
    const float4 z = make_float4(0.f, 0.f, 0.f, 0.f);
    if (idx < REG1) {
        int r6  = idx / ROW4;
        int rem = idx - r6 * ROW4;
        int r   = (r6 < 3) ? r6 : 48 + r6;            // 0,1,2,51,52,53
        Yb[r * ROW4 + rem] = z;
    } else {
        int i2  = idx - REG1;
        int r   = 3 + i2 / (8 * COLS4);               // 3..50
        int rem = i2 - (r - 3) * (8 * COLS4);
        int cg  = rem / COLS4;
        int c   = (cg < 3) ? cg : 48 + cg;            // 0,1,2,51..55
        int ch4 = rem - cg * COLS4;
        Yb[(r * RS + c) * COLS4 + ch4] = z;
    }
}

// ---------------------------------------------------------------------------
// Converter: W (768,256) fp32 -> Wt (768,512) bf16 split hi|lo.
// ---------------------------------------------------------------------------
__global__ __launch_bounds__(256) void convert_w(
    const float* __restrict__ W, short* __restrict__ Wt)
{
    int t = blockIdx.x * 256 + threadIdx.x;       // 0 .. 196607
    int o = t >> 8, c = t & 255;
    float v = W[t];
    unsigned short hi = f2bf_rne(v);
    unsigned short lo = f2bf_rne(v - bf2f(hi));
    Wt[(size_t)o * 512 + c]       = (short)hi;
    Wt[(size_t)o * 512 + 256 + c] = (short)lo;
}

// ---------------------------------------------------------------------------
// Converter: X (B,256,2304) fp32 -> Xt (B,2304,512) bf16 split hi|lo.
// ---------------------------------------------------------------------------
__global__ __launch_bounds__(256) void convert_x(
    const float* __restrict__ X, short* __restrict__ Xt)
{
    __shared__ float tile[64][65];
    const int t  = threadIdx.x;
    const int p0 = blockIdx.x * 64;   // 36
    const int c0 = blockIdx.y * 64;   // 4
    const int b  = blockIdx.z;

    const float* Xb = X + (size_t)b * CIN * PP;
    #pragma unroll
    for (int r = 0; r < 16; ++r) {
        int idx = r * 256 + t;
        int c = idx >> 6, p = idx & 63;
        tile[c][p] = Xb[(size_t)(c0 + c) * PP + p0 + p];
    }
    __syncthreads();
    short* Xo = Xt + (size_t)b * PP * 512;
    #pragma unroll
    for (int r = 0; r < 16; ++r) {
        int idx = r * 256 + t;
        int p = idx >> 6, c = idx & 63;
        float v = tile[c][p];
        unsigned short hi = f2bf_rne(v);
        unsigned short lo = f2bf_rne(v - bf2f(hi));
        size_t base = (size_t)(p0 + p) * 512 + c0 + c;
        Xo[base]       = (short)hi;
        Xo[base + 256] = (short)lo;
    }
}

// ---------------------------------------------------------------------------
// Kernel 1: conv as split-bf16 MFMA GEMM, 3-term product (r5-verified):
//   k0 in [0,256):   W hi x X hi ; [256,512): W hi x X lo ; [512,768): W lo x X hi
// Tile 64(o) x 64(p), grid 36x12x2 = 864 blocks (3.4/CU). 4 waves per block,
// each a 32x32 quadrant (2x2 MFMA 16x16x32).
// Staging (r6 bug fixed): threads 0..127 stage As, 128..255 stage Bs;
// 2 threads/row, 16 shorts (two uint4) each -> full 64x32 coverage per tile.
// ---------------------------------------------------------------------------
#define LDA 40   // shorts per LDS row (32 + 8 pad)

__global__ __launch_bounds__(256, 4) void conv_mfma(
    const short* __restrict__ Wt,   // (768, 512)
    const short* __restrict__ Xt,   // (B, 2304, 512)
    float* __restrict__ Y2)
{
    __shared__ short As[64 * LDA];   // [o][k]
    __shared__ short Bs[64 * LDA];   // [p][k]

    const int tid = threadIdx.x;
    const int bn  = blockIdx.x;       // p tile (36)
    const int bm  = blockIdx.y;       // o tile (12)
    const int b   = blockIdx.z;
    const int om0 = bm * 64, pn0 = bn * 64;

    const int lane = tid & 63, w = tid >> 6;
    const int oq = (w & 1) * 32, pq = (w >> 1) * 32;
    const int ln15 = lane & 15, q = lane >> 4;

    const int  lrow  = (tid & 127) >> 1;    // 0..63
    const int  lsoff = (tid & 1) * 16;      // 0 or 16 shorts
    const bool isA   = tid < 128;
    const short* gA = Wt + (size_t)(om0 + lrow) * 512 + lsoff;
    const short* gB = Xt + (size_t)b * PP * 512 + (size_t)(pn0 + lrow) * 512 + lsoff;
    const short* gsrc = isA ? gA : gB;
    short* ldst = (isA ? As : Bs) + lrow * LDA + lsoff;

    f32x4 acc[2][2] = {};

    for (int k0 = 0; k0 < 768; k0 += 32) {
        const int wk = (k0 < 256) ? k0 : k0 - 256;   // W: hi, hi, lo
        const int xk = (k0 < 512) ? k0 : k0 - 512;   // X: hi, lo, hi
        const int kk = isA ? wk : xk;
        uint4 v0 = *(const uint4*)(gsrc + kk);
        uint4 v1 = *(const uint4*)(gsrc + kk + 8);
        __syncthreads();
        *(uint4*)ldst       = v0;
        *(uint4*)(ldst + 8) = v1;
        __syncthreads();

        bf16x8 af[2], bf[2];
        #pragma unroll
        for (int i = 0; i < 2; ++i) {
            af[i] = *(const bf16x8*)&As[(oq + i * 16 + ln15) * LDA + q * 8];
            bf[i] = *(const bf16x8*)&Bs[(pq + i * 16 + ln15) * LDA + q * 8];
        }
        #pragma unroll
        for (int i = 0; i < 2; ++i)
            #pragma unroll
            for (int j = 0; j < 2; ++j)
                acc[i][j] = __builtin_amdgcn_mfma_f32_16x16x32_bf16(
                    af[i], bf[j], acc[i][j], 0, 0, 0);
    }

    // D[m=o][n=p]: lane = col p (ln15), rows o = q*4..q*4+3 contiguous
    float* Yb = Y2 + (size_t)b * BSTRIDE + IOFF;
    #pragma unroll
    for (int i = 0; i < 2; ++i) {
        #pragma unroll
        for (int j = 0; j < 2; ++j) {
            int o = om0 + oq + i * 16 + q * 4;
            int p = pn0 + pq + j * 16 + ln15;
            int h = p / 48, ww = p - h * 48;
            *(f32x4*)&Yb[(size_t)(h * RS + ww) * OC3 + o] = acc[i][j];
        }
    }
}

// ---------------------------------------------------------------------------
// Kernel 2: attention. One wave per (b,g,p'). XCD-swizzled. (r5, unchanged)
// ---------------------------------------------------------------------------
struct TagH { static constexpr bool value = true;  };
struct TagW { static constexpr bool value = false; };

__global__ __launch_bounds__(256, 4) void attn_kernel(
    const float* __restrict__ Y2,
    const float* __restrict__ rpe_h,  // (4,1,7,1,32)
    const float* __restrict__ rpe_w,  // (4,1,1,7,32)
    float* __restrict__ out)          // (B, 256, 48, 48)
{
    __shared__ float xpose[4][65];

    const int tid  = threadIdx.x;
    const int lane = tid & 63;
    const int w    = tid >> 6;
    const int bx     = blockIdx.x;
    const int wblock = (bx & 7) * 576 + (bx >> 3);
    const int wid    = wblock * 4 + w;
    const int pq   = wid % PP;
    const int g    = (wid / PP) & (NG - 1);
    const int b    = wid / (PP * NG);
    const int ph   = pq / 48;
    const int pw   = pq - ph * 48;

    const float* Yb = Y2 + (size_t)b * BSTRIDE + IOFF;

    const float qv = Yb[(size_t)(ph * RS + pw) * OC3 + g * GOC + lane];

    const int t   = (pq >= HALF_P) ? 1 : 0;
    const int qpr = pq - t * HALF_P;
    const int p0  = 2 * qpr;
    const int ph0 = p0 / 48;
    const int pw0 = p0 - ph0 * 48;
    const int g2  = 2 * g + t;
    const bool use_h = (g2 < NG);
    const int  kch   = use_h ? (CIN + g2 * GOC) : (CIN + (g2 - NG) * GOC + C2);
    const float* rb  = use_h ? (rpe_h + g2 * 7 * C2) : (rpe_w + (g2 - NG) * 7 * C2);

    const int  c  = lane & 31;
    const bool hi = (lane >= 32);

    const float R0 = rb[0 * C2 + c], R1 = rb[1 * C2 + c], R2 = rb[2 * C2 + c],
                R3 = rb[3 * C2 + c], R4 = rb[4 * C2 + c], R5 = rb[5 * C2 + c],
                R6 = rb[6 * C2 + c];

    const float* kb = Yb + (size_t)(ph0 * RS + pw0) * OC3 + kch + c;

    auto rget = [&](int idx) -> float {
        return idx == 0 ? R0 : idx == 1 ? R1 : idx == 2 ? R2 :
               idx == 3 ? R3 : idx == 4 ? R4 : idx == 5 ? R5 : R6;
    };

    auto tree = [&](auto tag) -> float {
        constexpr bool UH = decltype(tag)::value;
        auto chunkprod = [&](int l) -> float {
            int m0 = 2 * l,     h10 = (m0 >= KK), k0 = m0 - KK * h10;
            int m1 = 2 * l + 1, h11 = (m1 >= KK), k1 = m1 - KK * h11;
            int i0 = k0 / 7, j0 = k0 % 7, i1 = k1 / 7, j1 = k1 % 7;
            int d0 = ((i0 - 3) * RS + (h10 + j0 - 3)) * OC3;
            int d1 = ((i1 - 3) * RS + (h11 + j1 - 3)) * OC3;
            float kv = kb[hi ? d1 : d0];
            float ra = UH ? rget(i0) : rget(j0);
            float rc = UH ? rget(i1) : rget(j1);
            kv += hi ? rc : ra;
            return qv * kv;
        };
        float sv[32];
        #pragma unroll
        for (int jj = 0; jj < 32; ++jj) {
            if (2 * jj >= KK) { sv[jj] = 0.f; continue; }
            float pa = chunkprod(2 * jj);
            float pb = (2 * jj + 1 < KK) ? chunkprod(2 * jj + 1) : 0.f;
            float u  = (lane & 1) ? pb : pa;
            float ww = (lane & 1) ? pa : pb;
            sv[jj] = u + __shfl_xor(ww, 1, 64);
        }
        #pragma unroll
        for (int d = 2; d < 64; d <<= 1) {
            #pragma unroll
            for (int i = 0; i < 32; i += d) {
                float a  = sv[i], bb = sv[i + d / 2];
                float u  = (lane & d) ? bb : a;
                float ww = (lane & d) ? a : bb;
                sv[i] = u + __shfl_xor(ww, d, 64);
            }
        }
        return sv[0];
    };

    const float logit = use_h ? tree(TagH{}) : tree(TagW{});

    float mx = logit;
    #pragma unroll
    for (int d = 1; d < 64; d <<= 1)
        mx = fmaxf(mx, __shfl_xor(mx, d, 64));
    float e = (lane < KK) ? __expf(logit - mx) : 0.f;
    float ssum = e;
    #pragma unroll
    for (int d = 1; d < 64; d <<= 1)
        ssum += __shfl_xor(ssum, d, 64);
    const float att = e / ssum;

    float acc = 0.f;
    const float* vb = Yb + (size_t)(ph * RS + pw) * OC3 + 2 * CIN + g * GOC + lane;
    #pragma unroll
    for (int k = 0; k < KK; ++k) {
        int i = k / 7, j = k % 7;
        int doff = ((i - 3) * RS + (j - 3)) * OC3;
        float ak = __uint_as_float(
            __builtin_amdgcn_readlane(__float_as_uint(att), k));
        acc = fmaf(ak, vb[doff], acc);
    }

    xpose[w][lane] = acc;
    __syncthreads();
    const int wid0 = wblock * 4;
    const int pq0  = wid0 % PP;
    const int g0   = (wid0 / PP) & (NG - 1);
    const int b0   = wid0 / (PP * NG);
    const int ch   = tid >> 2;
    const int w2   = tid & 3;
    out[((size_t)b0 * 256 + g0 * GOC + ch) * PP + pq0 + w2] = xpose[w2][ch];
}

// ---------------------------------------------------------------------------
extern "C" void kernel_launch(void* const* d_in, const int* in_sizes, int n_in,
                              void* d_out, int out_size, void* d_ws, size_t ws_size,
                              hipStream_t stream)
{
    const float* x  = (const float*)d_in[0];
    const float* w  = (const float*)d_in[1];
    const float* rh = (const float*)d_in[2];
    const float* rw = (const float*)d_in[3];

    float* Y2 = (float*)d_ws;
    short* Xt = (short*)((char*)d_ws + XT_OFF);
    short* Wt = (short*)((char*)d_ws + WT_OFF);

    zero_guard<<<dim3(540, BB), 256, 0, stream>>>(Y2);
    convert_w<<<768, 256, 0, stream>>>(w, Wt);
    convert_x<<<dim3(36, 4, BB), 256, 0, stream>>>(x, Xt);

    conv_mfma<<<dim3(36, 12, BB), 256, 0, stream>>>(Wt, Xt, Y2);

    attn_kernel<<<(BB * NG * PP) / 4, 256, 0, stream>>>(Y2, rh, rw, (float*)d_out);
}